// Round 17
// baseline (425.183 us; speedup 1.0000x reference)
//
#include <hip/hip_runtime.h>
#include <hip/hip_bf16.h>

#define NTOK 65536      // 4 * 16384 tokens

typedef __attribute__((ext_vector_type(4))) float f32x4;
typedef __attribute__((ext_vector_type(8))) short bf16x8;

__device__ __forceinline__ float gelu_f(float x){
    float z = -2.30234438f * fmaf(0.044715f * x * x, x, x);
    float e = exp2f(z);
    return x * __builtin_amdgcn_rcpf(1.0f + e);
}
__device__ __forceinline__ float bf2f(unsigned short u){
    union { unsigned int i; float f; } w; w.i = ((unsigned int)u) << 16; return w.f;
}
__device__ __forceinline__ unsigned short f2bf(float f){
    __hip_bfloat16 h = __float2bfloat16(f);
    return *reinterpret_cast<unsigned short*>(&h);
}
__device__ __forceinline__ bf16x8 add_bf8(bf16x8 s, bf16x8 o, float k){
    bf16x8 r;
    #pragma unroll
    for (int i = 0; i < 8; i++)
        r[i] = (short)f2bf(fmaf(k, bf2f((unsigned short)o[i]), bf2f((unsigned short)s[i])));
    return r;
}

// ---------- weight fp32 -> bf16 conversion into contiguous Wb ----------
__global__ __launch_bounds__(256) void wconv_kernel(const float* __restrict__ q_w, const float* __restrict__ kv_w,
                                                    const float* __restrict__ op1_w, const float* __restrict__ op2_w,
                                                    const float* __restrict__ om1_w, const float* __restrict__ om2_w,
                                                    const float* __restrict__ fc1_w, const float* __restrict__ fc2_w,
                                                    unsigned short* __restrict__ Wb){
    size_t e = ((size_t)blockIdx.x * 256 + threadIdx.x) * 4;
    if (e >= 753664) return;
    const float* src; size_t off;
    if      (e <  65536){ src = q_w;   off = 0; }
    else if (e < 196608){ src = kv_w;  off = 65536; }
    else if (e < 262144){ src = op1_w; off = 196608; }
    else if (e < 327680){ src = op2_w; off = 262144; }
    else if (e < 344064){ src = om1_w; off = 327680; }
    else if (e < 360448){ src = om2_w; off = 344064; }
    else if (e < 557056){ src = fc1_w; off = 360448; }
    else                { src = fc2_w; off = 557056; }
    float4 v = *reinterpret_cast<const float4*>(src + (e - off));
    ushort4 o; o.x = f2bf(v.x); o.y = f2bf(v.y); o.z = f2bf(v.z); o.w = f2bf(v.w);
    *reinterpret_cast<ushort4*>(Wb + e) = o;
}

// ---------- std LayerNorm over 256 -> bf16 out; wave-per-token, 8 tokens/wave ----------
template<bool BF16IN>
__global__ __launch_bounds__(256) void stdln_kernel(const void* __restrict__ Xp,
                                                    const float* __restrict__ w,
                                                    const float* __restrict__ b,
                                                    unsigned short* __restrict__ out){
    int wv = threadIdx.x >> 6, lane = threadIdx.x & 63;
    int tok0 = (blockIdx.x * 4 + wv) * 8;
    int c0 = lane * 4;
    float4 w4 = *reinterpret_cast<const float4*>(w + c0);
    float4 b4 = *reinterpret_cast<const float4*>(b + c0);
    #pragma unroll 2
    for (int j = 0; j < 8; j++){
        size_t base = (size_t)(tok0 + j) * 256 + c0;
        float v[4];
        if constexpr (BF16IN){
            ushort4 u = *reinterpret_cast<const ushort4*>((const unsigned short*)Xp + base);
            v[0] = bf2f(u.x); v[1] = bf2f(u.y); v[2] = bf2f(u.z); v[3] = bf2f(u.w);
        } else {
            float4 f = *reinterpret_cast<const float4*>((const float*)Xp + base);
            v[0] = f.x; v[1] = f.y; v[2] = f.z; v[3] = f.w;
        }
        float s = v[0] + v[1] + v[2] + v[3];
        #pragma unroll
        for (int m = 1; m < 64; m <<= 1) s += __shfl_xor(s, m, 64);
        float mean = s * (1.0f / 256.0f);
        float ss = 0;
        #pragma unroll
        for (int k = 0; k < 4; k++){ v[k] -= mean; ss = fmaf(v[k], v[k], ss); }
        #pragma unroll
        for (int m = 1; m < 64; m <<= 1) ss += __shfl_xor(ss, m, 64);
        float inv = rsqrtf(ss * (1.0f / 256.0f) + 1e-5f);
        ushort4 o;
        o.x = f2bf(w4.x * v[0] * inv + b4.x);
        o.y = f2bf(w4.y * v[1] * inv + b4.y);
        o.z = f2bf(w4.z * v[2] * inv + b4.z);
        o.w = f2bf(w4.w * v[3] * inv + b4.w);
        *reinterpret_cast<ushort4*>(out + base) = o;
    }
}

// ---------- ce_flat = cor @ cor_w.T (K=2), token-blocked ----------
__global__ __launch_bounds__(256) void ce_kernel(const float* __restrict__ cor,
                                                 const float* __restrict__ cor_w,
                                                 unsigned short* __restrict__ CEF){
    int m = threadIdx.x & 127, half = threadIdx.x >> 7;
    float w0 = cor_w[m * 2 + 0], w1 = cor_w[m * 2 + 1];
    #pragma unroll 4
    for (int it = 0; it < 16; it++){
        int tok = blockIdx.x * 32 + it * 2 + half;
        float c0 = cor[(size_t)tok * 2 + 0];
        float c1 = cor[(size_t)tok * 2 + 1];
        CEF[(size_t)tok * 128 + m] = f2bf(c0 * w0 + c1 * w1);
    }
}

// ---------- fused: on-the-fly custom LN of K,V,CE + ktv & ktc reductions ----------
__global__ __launch_bounds__(256) void ktvc_kernel(const unsigned short* __restrict__ Kb,
                                                   const unsigned short* __restrict__ Vb,
                                                   const unsigned short* __restrict__ CEF,
                                                   const float* __restrict__ kw, const float* __restrict__ kbb,
                                                   const float* __restrict__ vw, const float* __restrict__ vbb,
                                                   const float* __restrict__ cw, const float* __restrict__ cbb,
                                                   float* __restrict__ KTV, float* __restrict__ KTC){
    int bh = blockIdx.x, b = bh >> 3, h = bh & 7;
    __shared__ float Ks[64][36];
    __shared__ float Vs[64][36];
    __shared__ float Cs[64][20];
    __shared__ float P[2][64][24];
    int t = threadIdx.x;
    int lr = t >> 2, lq = t & 3;
    int g = t >> 6, tl = t & 63;
    int d0 = (tl >> 3) * 4, e0 = (tl & 7) * 4, e0c = (tl & 7) * 2;
    float kwr[8], kbr[8], vwr[8], vbr[8], cwr[4], cbr[4];
    #pragma unroll
    for (int j = 0; j < 8; j++){
        kwr[j] = kw[h * 32 + lq * 8 + j]; kbr[j] = kbb[h * 32 + lq * 8 + j];
        vwr[j] = vw[h * 32 + lq * 8 + j]; vbr[j] = vbb[h * 32 + lq * 8 + j];
    }
    #pragma unroll
    for (int j = 0; j < 4; j++){
        cwr[j] = cw[h * 16 + lq * 4 + j]; cbr[j] = cbb[h * 16 + lq * 4 + j];
    }
    float akv[4][4] = {};
    float akc[4][2] = {};
    size_t base = ((size_t)b << 14) + (size_t)blockIdx.y * 512;
    for (int n0 = 0; n0 < 512; n0 += 64){
        size_t rowi = base + n0 + lr;
        const ushort4* kp = reinterpret_cast<const ushort4*>(Kb + rowi * 256 + h * 32 + lq * 8);
        ushort4 ka = kp[0], kc = kp[1];
        const ushort4* vp = reinterpret_cast<const ushort4*>(Vb + rowi * 256 + h * 32 + lq * 8);
        ushort4 va = vp[0], vc = vp[1];
        ushort4 ca = *reinterpret_cast<const ushort4*>(CEF + rowi * 128 + h * 16 + lq * 4);
        float kvv[8] = { bf2f(ka.x), bf2f(ka.y), bf2f(ka.z), bf2f(ka.w),
                         bf2f(kc.x), bf2f(kc.y), bf2f(kc.z), bf2f(kc.w) };
        float vvv[8] = { bf2f(va.x), bf2f(va.y), bf2f(va.z), bf2f(va.w),
                         bf2f(vc.x), bf2f(vc.y), bf2f(vc.z), bf2f(vc.w) };
        float cvv[4] = { bf2f(ca.x), bf2f(ca.y), bf2f(ca.z), bf2f(ca.w) };
        float s = 0;
        #pragma unroll
        for (int j = 0; j < 8; j++) s += kvv[j];
        s += __shfl_xor(s, 1, 64); s += __shfl_xor(s, 2, 64);
        float mean = s * (1.0f / 32.0f);
        float ss = 0;
        #pragma unroll
        for (int j = 0; j < 8; j++){ kvv[j] -= mean; ss = fmaf(kvv[j], kvv[j], ss); }
        ss += __shfl_xor(ss, 1, 64); ss += __shfl_xor(ss, 2, 64);
        float inv = 1.0f / (sqrtf(ss * (1.0f / 31.0f)) + 1e-5f);
        #pragma unroll
        for (int j = 0; j < 8; j++) kvv[j] = fmaf(kwr[j] * kvv[j], inv, kbr[j]);
        s = 0;
        #pragma unroll
        for (int j = 0; j < 8; j++) s += vvv[j];
        s += __shfl_xor(s, 1, 64); s += __shfl_xor(s, 2, 64);
        mean = s * (1.0f / 32.0f);
        ss = 0;
        #pragma unroll
        for (int j = 0; j < 8; j++){ vvv[j] -= mean; ss = fmaf(vvv[j], vvv[j], ss); }
        ss += __shfl_xor(ss, 1, 64); ss += __shfl_xor(ss, 2, 64);
        inv = 1.0f / (sqrtf(ss * (1.0f / 31.0f)) + 1e-5f);
        #pragma unroll
        for (int j = 0; j < 8; j++) vvv[j] = fmaf(vwr[j] * vvv[j], inv, vbr[j]);
        s = 0;
        #pragma unroll
        for (int j = 0; j < 4; j++) s += cvv[j];
        s += __shfl_xor(s, 1, 64); s += __shfl_xor(s, 2, 64);
        mean = s * (1.0f / 16.0f);
        ss = 0;
        #pragma unroll
        for (int j = 0; j < 4; j++){ cvv[j] -= mean; ss = fmaf(cvv[j], cvv[j], ss); }
        ss += __shfl_xor(ss, 1, 64); ss += __shfl_xor(ss, 2, 64);
        inv = 1.0f / (sqrtf(ss * (1.0f / 15.0f)) + 1e-5f);
        #pragma unroll
        for (int j = 0; j < 4; j++) cvv[j] = fmaf(cwr[j] * cvv[j], inv, cbr[j]);
        __syncthreads();
        #pragma unroll
        for (int j = 0; j < 8; j++){ Ks[lr][lq * 8 + j] = kvv[j]; Vs[lr][lq * 8 + j] = vvv[j]; }
        #pragma unroll
        for (int j = 0; j < 4; j++) Cs[lr][lq * 4 + j] = cvv[j];
        __syncthreads();
        #pragma unroll 4
        for (int i = 0; i < 16; i++){
            int n = g * 16 + i;
            float4 k4 = *reinterpret_cast<const float4*>(&Ks[n][d0]);
            float4 v4 = *reinterpret_cast<const float4*>(&Vs[n][e0]);
            float2 c2 = *reinterpret_cast<const float2*>(&Cs[n][e0c]);
            float kk[4] = { k4.x, k4.y, k4.z, k4.w };
            float vv[4] = { v4.x, v4.y, v4.z, v4.w };
            #pragma unroll
            for (int a = 0; a < 4; a++){
                akv[a][0] = fmaf(kk[a], vv[0], akv[a][0]);
                akv[a][1] = fmaf(kk[a], vv[1], akv[a][1]);
                akv[a][2] = fmaf(kk[a], vv[2], akv[a][2]);
                akv[a][3] = fmaf(kk[a], vv[3], akv[a][3]);
                akc[a][0] = fmaf(kk[a], c2.x, akc[a][0]);
                akc[a][1] = fmaf(kk[a], c2.y, akc[a][1]);
            }
        }
    }
    __syncthreads();
    if (g >= 2){
        float* p = &P[g - 2][tl][0];
        #pragma unroll
        for (int a = 0; a < 4; a++){
            #pragma unroll
            for (int e = 0; e < 4; e++) p[a * 4 + e] = akv[a][e];
            p[16 + a * 2 + 0] = akc[a][0];
            p[16 + a * 2 + 1] = akc[a][1];
        }
    }
    __syncthreads();
    if (g < 2){
        const float* p = &P[g][tl][0];
        #pragma unroll
        for (int a = 0; a < 4; a++){
            #pragma unroll
            for (int e = 0; e < 4; e++) akv[a][e] += p[a * 4 + e];
            akc[a][0] += p[16 + a * 2 + 0];
            akc[a][1] += p[16 + a * 2 + 1];
        }
    }
    __syncthreads();
    if (g == 1){
        float* p = &P[0][tl][0];
        #pragma unroll
        for (int a = 0; a < 4; a++){
            #pragma unroll
            for (int e = 0; e < 4; e++) p[a * 4 + e] = akv[a][e];
            p[16 + a * 2 + 0] = akc[a][0];
            p[16 + a * 2 + 1] = akc[a][1];
        }
    }
    __syncthreads();
    if (g == 0){
        const float* p = &P[0][tl][0];
        const float sc = 1.0f / 16384.0f;
        float* o = KTV + (size_t)bh * 1024;
        float* o2 = KTC + (size_t)bh * 512;
        #pragma unroll
        for (int a = 0; a < 4; a++){
            #pragma unroll
            for (int e = 0; e < 4; e++)
                atomicAdd(&o[(d0 + a) * 32 + e0 + e], (akv[a][e] + p[a * 4 + e]) * sc);
            atomicAdd(&o2[(d0 + a) * 16 + e0c + 0], (akc[a][0] + p[16 + a * 2 + 0]) * sc);
            atomicAdd(&o2[(d0 + a) * 16 + e0c + 1], (akc[a][1] + p[16 + a * 2 + 1]) * sc);
        }
    }
}

// ---------- combined attention weights ----------
__global__ __launch_bounds__(256) void wcomb_kernel(const float* __restrict__ q_w,
                                                    const float* __restrict__ KTV,
                                                    const float* __restrict__ KTC,
                                                    unsigned short* __restrict__ WTC){
    int c = blockIdx.x;
    int b = blockIdx.y;
    int i = threadIdx.x;
    __shared__ float coef[32];
    int h = (c < 256) ? (c >> 5) : ((c - 256) >> 4);
    if (i < 32){
        if (c < 256) coef[i] = KTV[(size_t)((b * 8 + h) << 10) + i * 32 + (c & 31)];
        else         coef[i] = KTC[(size_t)((b * 8 + h) << 9)  + i * 16 + ((c - 256) & 15)];
    }
    __syncthreads();
    float acc = 0;
    #pragma unroll
    for (int d = 0; d < 32; d++) acc = fmaf(q_w[(size_t)(h * 32 + d) * 256 + i], coef[d], acc);
    WTC[((size_t)b * 384 + c) * 256 + i] = f2bf(acc);
}

// ---------- fused motion MLP: mout = gelu(dm @ om1.T + b1) @ om2.T + b2 ----------
__global__ __launch_bounds__(256) void motion_kernel(const unsigned short* __restrict__ TM,
                                                     const unsigned short* __restrict__ w1,
                                                     const float* __restrict__ b1,
                                                     const unsigned short* __restrict__ w2,
                                                     const float* __restrict__ b2,
                                                     float* __restrict__ mout){
    __shared__ __align__(16) unsigned short SMEM[32768];
    unsigned short* STG = SMEM;
    unsigned short* MH  = SMEM + 16384;
    const int t = threadIdx.x;
    const int lane = t & 63, wid = t >> 6;
    const int wm = wid & 1, wn = wid >> 1;
    const int row0 = blockIdx.x * 128;
    const int lr = lane >> 2;
    const int ls = lane & 3;
    const int kq = lane >> 4;
    const int rr = lane & 15;
    f32x4 acc[4][4];
    #pragma unroll
    for (int i = 0; i < 4; i++)
        #pragma unroll
        for (int j = 0; j < 4; j++){ f32x4 z = {0.f, 0.f, 0.f, 0.f}; acc[i][j] = z; }

    auto STAGE1 = [&](int buf, int kb){
        #pragma unroll
        for (int c = wid; c < 16; c += 4){
            int r16 = (c < 8) ? c : (c - 8);
            int row = r16 * 16 + lr;
            int ko = ls ^ ((row >> 1) & 3);
            if (c < 8){
                __builtin_amdgcn_global_load_lds(
                    (const __attribute__((address_space(1))) unsigned int*)(TM + (size_t)(row0 + row) * 128 + kb + ko * 8),
                    (__attribute__((address_space(3))) unsigned int*)(STG + buf * 4096 + r16 * 512),
                    16, 0, 0);
            } else {
                __builtin_amdgcn_global_load_lds(
                    (const __attribute__((address_space(1))) unsigned int*)(w1 + (size_t)row * 128 + kb + ko * 8),
                    (__attribute__((address_space(3))) unsigned int*)(STG + 8192 + buf * 4096 + r16 * 512),
                    16, 0, 0);
            }
        }
    };

    STAGE1(0, 0);
    asm volatile("s_waitcnt vmcnt(0)" ::: "memory");
    __builtin_amdgcn_s_barrier();
    #pragma unroll 1
    for (int tt = 0; tt < 4; tt++){
        int cur = tt & 1;
        if (tt + 1 < 4) STAGE1(cur ^ 1, (tt + 1) * 32);
        bf16x8 af[4], bfr[4];
        #pragma unroll
        for (int m = 0; m < 4; m++){
            int row = wm * 64 + m * 16 + rr;
            int s = kq ^ ((row >> 1) & 3);
            af[m] = *reinterpret_cast<const bf16x8*>(STG + cur * 4096 + row * 32 + s * 8);
        }
        #pragma unroll
        for (int n = 0; n < 4; n++){
            int row = wn * 64 + n * 16 + rr;
            int s = kq ^ ((row >> 1) & 3);
            bfr[n] = *reinterpret_cast<const bf16x8*>(STG + 8192 + cur * 4096 + row * 32 + s * 8);
        }
        #pragma unroll
        for (int m = 0; m < 4; m++)
            #pragma unroll
            for (int n = 0; n < 4; n++)
                acc[m][n] = __builtin_amdgcn_mfma_f32_16x16x32_bf16(af[m], bfr[n], acc[m][n], 0, 0, 0);
        if (tt + 1 < 4){
            asm volatile("s_waitcnt vmcnt(0)" ::: "memory");
            __builtin_amdgcn_s_barrier();
        }
    }

    __builtin_amdgcn_s_barrier();
    #pragma unroll
    for (int c = wid; c < 32; c += 4){
        int kt = c >> 3, r16 = c & 7;
        int row = r16 * 16 + lr;
        int ko = ls ^ ((row >> 1) & 3);
        __builtin_amdgcn_global_load_lds(
            (const __attribute__((address_space(1))) unsigned int*)(w2 + (size_t)row * 128 + kt * 32 + ko * 8),
            (__attribute__((address_space(3))) unsigned int*)(STG + kt * 4096 + r16 * 512),
            16, 0, 0);
    }
    #pragma unroll
    for (int m = 0; m < 4; m++){
        #pragma unroll
        for (int n = 0; n < 4; n++){
            int col = wn * 64 + n * 16 + rr;
            float bb = b1[col];
            int kt = col >> 5, ck = col & 31;
            #pragma unroll
            for (int j = 0; j < 4; j++){
                int r = wm * 64 + m * 16 + kq * 4 + j;
                int ps = (ck >> 3) ^ ((r >> 1) & 3);
                MH[kt * 4096 + r * 32 + ps * 8 + (ck & 7)] = f2bf(gelu_f(acc[m][n][j] + bb));
            }
        }
    }
    asm volatile("s_waitcnt vmcnt(0)" ::: "memory");
    __syncthreads();

    f32x4 acc2[4][4];
    #pragma unroll
    for (int i = 0; i < 4; i++)
        #pragma unroll
        for (int j = 0; j < 4; j++){ f32x4 z = {0.f, 0.f, 0.f, 0.f}; acc2[i][j] = z; }
    #pragma unroll
    for (int tt = 0; tt < 4; tt++){
        bf16x8 af[4], bfr[4];
        #pragma unroll
        for (int m = 0; m < 4; m++){
            int row = wm * 64 + m * 16 + rr;
            int s = kq ^ ((row >> 1) & 3);
            af[m] = *reinterpret_cast<const bf16x8*>(MH + tt * 4096 + row * 32 + s * 8);
        }
        #pragma unroll
        for (int n = 0; n < 4; n++){
            int row = wn * 64 + n * 16 + rr;
            int s = kq ^ ((row >> 1) & 3);
            bfr[n] = *reinterpret_cast<const bf16x8*>(STG + tt * 4096 + row * 32 + s * 8);
        }
        #pragma unroll
        for (int m = 0; m < 4; m++)
            #pragma unroll
            for (int n = 0; n < 4; n++)
                acc2[m][n] = __builtin_amdgcn_mfma_f32_16x16x32_bf16(af[m], bfr[n], acc2[m][n], 0, 0, 0);
    }

    __syncthreads();
    float* scrf = (float*)MH + (size_t)wid * 1088;
    const int rloc = lane >> 2;
    const int cs = (lane & 3) * 16;
    #pragma unroll
    for (int m = 0; m < 4; m++){
        #pragma unroll
        for (int n = 0; n < 4; n++){
            int col = wn * 64 + n * 16 + rr;
            float bb = b2[col];
            #pragma unroll
            for (int j = 0; j < 4; j++)
                scrf[(kq * 4 + j) * 68 + n * 16 + rr] = acc2[m][n][j] + bb;
        }
        int r = row0 + wm * 64 + m * 16 + rloc;
        int colb = wn * 64 + cs;
        #pragma unroll
        for (int q = 0; q < 4; q++){
            float4 vv = *reinterpret_cast<const float4*>(&scrf[rloc * 68 + cs + q * 4]);
            *reinterpret_cast<float4*>(&mout[(size_t)r * 128 + colb + q * 4]) = vv;
        }
    }
}

// ---------- depthwise 3x3 conv (SAME) + bias + gelu, y-banded (4 rows) x 16-col chunks ----------
__global__ __launch_bounds__(192) void dwconv_kernel(const unsigned short* __restrict__ H1,
                                                     const float* __restrict__ dww,
                                                     const float* __restrict__ dwb,
                                                     unsigned short* __restrict__ H2){
    int blk = blockIdx.x;
    int xq = blk & 7;
    int yb = (blk >> 3) & 31;
    int bb = blk >> 8;
    int y0 = yb * 4, x0 = xq * 16;
    int ch = threadIdx.x * 4;
    float w[9][4];
    #pragma unroll
    for (int k = 0; k < 9; k++)
        #pragma unroll
        for (int j = 0; j < 4; j++) w[k][j] = dww[(ch + j) * 9 + k];
    float bias[4] = { dwb[ch], dwb[ch+1], dwb[ch+2], dwb[ch+3] };
    size_t rb[6]; bool rv[6];
    #pragma unroll
    for (int r = 0; r < 6; r++){
        int yr = y0 - 1 + r;
        rv[r] = ((unsigned)yr <= 127u);
        int yc = yr < 0 ? 0 : (yr > 127 ? 127 : yr);
        rb[r] = ((size_t)((bb << 14) + (yc << 7))) * 768 + ch;
    }
    size_t ob[4];
    #pragma unroll
    for (int j = 0; j < 4; j++) ob[j] = ((size_t)((bb << 14) + ((y0 + j) << 7))) * 768 + ch;

    ushort4 cA[6], cB[6], cC[6], cD[6];
    const ushort4 Z = {0, 0, 0, 0};
    #define LOADR(DST, XX) do {                                               \
        int _x = (XX);                                                        \
        bool xv = ((unsigned)_x <= 127u);                                     \
        _Pragma("unroll")                                                     \
        for (int r = 0; r < 6; r++)                                           \
            DST[r] = (xv && rv[r]) ? *reinterpret_cast<const ushort4*>(H1 + rb[r] + (size_t)_x * 768) : Z; \
    } while (0)

    #define EMITB(SA, SB, SC, XX) do {                                        \
        _Pragma("unroll")                                                     \
        for (int j = 0; j < 4; j++){                                          \
            float acc[4];                                                     \
            _Pragma("unroll")                                                 \
            for (int q = 0; q < 4; q++) acc[q] = bias[q];                     \
            _Pragma("unroll")                                                 \
            for (int rr2 = 0; rr2 < 3; rr2++){                                \
                int ri = j + rr2;                                             \
                float a0=bf2f(SA[ri].x),a1=bf2f(SA[ri].y),a2=bf2f(SA[ri].z),a3=bf2f(SA[ri].w); \
                float b0=bf2f(SB[ri].x),b1=bf2f(SB[ri].y),b2=bf2f(SB[ri].z),b3=bf2f(SB[ri].w); \
                float c0=bf2f(SC[ri].x),c1=bf2f(SC[ri].y),c2=bf2f(SC[ri].z),c3=bf2f(SC[ri].w); \
                acc[0]=fmaf(a0,w[rr2*3+0][0],acc[0]); acc[0]=fmaf(b0,w[rr2*3+1][0],acc[0]); acc[0]=fmaf(c0,w[rr2*3+2][0],acc[0]); \
                acc[1]=fmaf(a1,w[rr2*3+0][1],acc[1]); acc[1]=fmaf(b1,w[rr2*3+1][1],acc[1]); acc[1]=fmaf(c1,w[rr2*3+2][1],acc[1]); \
                acc[2]=fmaf(a2,w[rr2*3+0][2],acc[2]); acc[2]=fmaf(b2,w[rr2*3+1][2],acc[2]); acc[2]=fmaf(c2,w[rr2*3+2][2],acc[2]); \
                acc[3]=fmaf(a3,w[rr2*3+0][3],acc[3]); acc[3]=fmaf(b3,w[rr2*3+1][3],acc[3]); acc[3]=fmaf(c3,w[rr2*3+2][3],acc[3]); \
            }                                                                 \
            ushort4 o;                                                        \
            o.x = f2bf(gelu_f(acc[0])); o.y = f2bf(gelu_f(acc[1]));           \
            o.z = f2bf(gelu_f(acc[2])); o.w = f2bf(gelu_f(acc[3]));           \
            *reinterpret_cast<ushort4*>(H2 + ob[j] + (size_t)(XX) * 768) = o; \
        }                                                                     \
    } while (0)

    LOADR(cD, x0 - 1);
    LOADR(cA, x0);
    LOADR(cB, x0 + 1);
    LOADR(cC, x0 + 2);
    #pragma unroll 1
    for (int g = 0; g < 4; g++){
        int x = x0 + g * 4;
        EMITB(cD, cA, cB, x);     LOADR(cD, x + 3);
        EMITB(cA, cB, cC, x + 1); LOADR(cA, x + 4);
        EMITB(cB, cC, cD, x + 2); LOADR(cB, x + 5);
        EMITB(cC, cD, cA, x + 3); LOADR(cC, x + 6);
    }
    #undef LOADR
    #undef EMITB
}

// ---------- bf16 MFMA GEMM, wide-N, drain pipeline, WM M-wave-groups, coalesced repack epilogue ----------
#define M_KV        1
#define M_BIAS_GELU 2
#define M_BIAS_BF16 5
#define M_BIAS_ADDX 6
#define M_ATTN      7
#define M_ADD2LN    8

template<int MODE, bool SWAP, int K, int O, int WN, int WM>
__global__ __launch_bounds__(64 * WN * WM) void mgemm(const unsigned short* __restrict__ A,
                                                      const unsigned short* __restrict__ Wp,
                                                      const float* __restrict__ bias,
                                                      const void* __restrict__ add,
                                                      const float* __restrict__ nw,
                                                      const float* __restrict__ nb,
                                                      void* __restrict__ out0,
                                                      void* __restrict__ out1){
    constexpr int WAVES = WM * WN;
    constexpr int BN = 64 * WN;
    constexpr int AR = 64 * WM;            // A rows per block
    constexpr int ACH = 4 * WM;            // A 16-row chunks
    constexpr int CH = ACH + 4 * WN;
    constexpr int NT = K / 32;
    constexpr int ATILE = AR * 32;         // shorts per A buffer
    constexpr bool F32OUT = (MODE == M_BIAS_ADDX);
    __shared__ __align__(16) unsigned short SMEM[2 * ATILE + 2 * BN * 32];
    unsigned short* As0 = SMEM;
    unsigned short* Bs0 = SMEM + 2 * ATILE;
    const int t = threadIdx.x;
    const int lane = t & 63, wid = t >> 6;
    const int wm = (WM == 1) ? 0 : (wid & 1);
    const int wn = (WM == 1) ? wid : (wid >> 1);
    const int row0 = blockIdx.x * AR;
    const int colB = blockIdx.y * BN;
    const unsigned short* W = Wp;
    if constexpr (MODE == M_ATTN) W += (size_t)(row0 >> 14) * (384 * 256);
    f32x4 acc[4][4];
    #pragma unroll
    for (int i = 0; i < 4; i++)
        #pragma unroll
        for (int j = 0; j < 4; j++){ f32x4 z = {0.f, 0.f, 0.f, 0.f}; acc[i][j] = z; }

    const int lr = lane >> 2;
    const int ls = lane & 3;
    const int kq = lane >> 4;
    const int rr = lane & 15;

    auto STAGE = [&](int buf, int kb){
        #pragma unroll
        for (int c = wid; c < CH; c += WAVES){
            int r16 = (c < ACH) ? c : (c - ACH);
            int row = r16 * 16 + lr;
            int ko = ls ^ ((row >> 1) & 3);
            if (c < ACH){
                int ga = row0 + row;
                if (SWAP) ga ^= 32768;
                __builtin_amdgcn_global_load_lds(
                    (const __attribute__((address_space(1))) unsigned int*)(A + (size_t)ga * K + kb + ko * 8),
                    (__attribute__((address_space(3))) unsigned int*)(As0 + buf * ATILE + r16 * 512),
                    16, 0, 0);
            } else {
                int gc = colB + row;
                __builtin_amdgcn_global_load_lds(
                    (const __attribute__((address_space(1))) unsigned int*)(W + (size_t)gc * K + kb + ko * 8),
                    (__attribute__((address_space(3))) unsigned int*)(Bs0 + buf * (BN * 32) + r16 * 512),
                    16, 0, 0);
            }
        }
    };

    STAGE(0, 0);
    asm volatile("s_waitcnt vmcnt(0)" ::: "memory");
    __builtin_amdgcn_s_barrier();
    #pragma unroll 1
    for (int tt = 0; tt < NT; tt++){
        int cur = tt & 1;
        if (tt + 1 < NT) STAGE(cur ^ 1, (tt + 1) * 32);
        bf16x8 af[4], bfr[4];
        #pragma unroll
        for (int m = 0; m < 4; m++){
            int row = wm * 64 + m * 16 + rr;
            int s = kq ^ ((row >> 1) & 3);
            af[m] = *reinterpret_cast<const bf16x8*>(As0 + cur * ATILE + row * 32 + s * 8);
        }
        #pragma unroll
        for (int n = 0; n < 4; n++){
            int row = wn * 64 + n * 16 + rr;
            int s = kq ^ ((row >> 1) & 3);
            bfr[n] = *reinterpret_cast<const bf16x8*>(Bs0 + cur * (BN * 32) + row * 32 + s * 8);
        }
        #pragma unroll
        for (int m = 0; m < 4; m++)
            #pragma unroll
            for (int n = 0; n < 4; n++)
                acc[m][n] = __builtin_amdgcn_mfma_f32_16x16x32_bf16(af[m], bfr[n], acc[m][n], 0, 0, 0);
        if (tt + 1 < NT){
            asm volatile("s_waitcnt vmcnt(0)" ::: "memory");
            __builtin_amdgcn_s_barrier();
        }
    }

    // ---- epilogue ----
    __syncthreads();
    unsigned short* scr = SMEM + (size_t)wid * 2304;
    float* scrf = (float*)scr;
    const int rloc = lane >> 2;
    const int cs = (lane & 3) * 16;

    if constexpr (MODE == M_ADD2LN){
        float* rowS = (float*)(SMEM + 20480);   // [4][128] floats
        float* rowQ = rowS + 512;               // [4][128]
        #pragma unroll
        for (int m = 0; m < 4; m++){
            #pragma unroll
            for (int j = 0; j < 4; j++){
                int r = row0 + wm * 64 + m * 16 + kq * 4 + j;
                float s = 0, q = 0;
                #pragma unroll
                for (int n = 0; n < 4; n++){
                    int col = wn * 64 + n * 16 + rr;
                    float v = acc[m][n][j] + bias[col]
                            + 2.0f * bf2f(((const unsigned short*)add)[(size_t)r * 256 + col]);
                    acc[m][n][j] = v;
                    s += v; q = fmaf(v, v, q);
                }
                s += __shfl_xor(s, 1, 64); s += __shfl_xor(s, 2, 64);
                s += __shfl_xor(s, 4, 64); s += __shfl_xor(s, 8, 64);
                q += __shfl_xor(q, 1, 64); q += __shfl_xor(q, 2, 64);
                q += __shfl_xor(q, 4, 64); q += __shfl_xor(q, 8, 64);
                if (rr == 0){
                    int lrow = wm * 64 + m * 16 + kq * 4 + j;
                    rowS[wn * 128 + lrow] = s;
                    rowQ[wn * 128 + lrow] = q;
                }
            }
        }
        __syncthreads();
        #pragma unroll
        for (int m = 0; m < 4; m++){
            #pragma unroll
            for (int n = 0; n < 4; n++){
                int col = wn * 64 + n * 16 + rr;
                float w2 = nw[col], b2 = nb[col];
                #pragma unroll
                for (int j = 0; j < 4; j++){
                    int lrow = wm * 64 + m * 16 + kq * 4 + j;
                    float S = rowS[lrow] + rowS[128 + lrow] + rowS[256 + lrow] + rowS[384 + lrow];
                    float Q = rowQ[lrow] + rowQ[128 + lrow] + rowQ[256 + lrow] + rowQ[384 + lrow];
                    float mean = S * (1.0f / 256.0f);
                    float var = fmaxf(Q * (1.0f / 256.0f) - mean * mean, 0.0f);
                    float inv = rsqrtf(var + 1e-5f);
                    float y = w2 * (acc[m][n][j] - mean) * inv + b2;
                    scr[(kq * 4 + j) * 68 + n * 16 + rr] = f2bf(y);
                }
            }
            int r = row0 + wm * 64 + m * 16 + rloc;
            #pragma unroll
            for (int q = 0; q < 2; q++){
                bf16x8 sv = *reinterpret_cast<const bf16x8*>(&scr[rloc * 68 + cs + q * 8]);
                int cg = wn * 64 + cs + q * 8;
                *reinterpret_cast<bf16x8*>((unsigned short*)out0 + (size_t)r * O + cg) = sv;
            }
        }
        return;
    }

    #pragma unroll
    for (int m = 0; m < 4; m++){
        #pragma unroll
        for (int n = 0; n < 4; n++){
            int col = colB + wn * 64 + n * 16 + rr;
            #pragma unroll
            for (int j = 0; j < 4; j++){
                float v = acc[m][n][j];
                int si = (kq * 4 + j) * 68 + n * 16 + rr;
                if constexpr (MODE == M_KV)            scr[si] = f2bf(v);
                else if constexpr (MODE == M_BIAS_GELU) scr[si] = f2bf(gelu_f(v + bias[col]));
                else if constexpr (MODE == M_BIAS_BF16) scr[si] = f2bf(v + bias[col]);
                else if constexpr (MODE == M_ATTN)      scr[si] = f2bf(v);
                else if constexpr (MODE == M_BIAS_ADDX) scrf[si] = v + bias[col];
            }
        }
        int r = row0 + wm * 64 + m * 16 + rloc;
        int colb = colB + wn * 64 + cs;
        if constexpr (F32OUT){
            #pragma unroll
            for (int q = 0; q < 4; q++){
                float4 vv = *reinterpret_cast<const float4*>(&scrf[rloc * 68 + cs + q * 4]);
                size_t o = (size_t)r * O + colb + q * 4;
                float4 xa = *reinterpret_cast<const float4*>(&((const float*)add)[o]);
                vv.x += xa.x; vv.y += xa.y; vv.z += xa.z; vv.w += xa.w;
                *reinterpret_cast<float4*>(&((float*)out0)[o]) = vv;
            }
        } else {
            #pragma unroll
            for (int q = 0; q < 2; q++){
                bf16x8 sv = *reinterpret_cast<const bf16x8*>(&scr[rloc * 68 + cs + q * 8]);
                int cg = colb + q * 8;
                if constexpr (MODE == M_KV){
                    unsigned short* dst = (cg < 256)
                        ? (unsigned short*)out0 + (size_t)r * 256 + cg
                        : (unsigned short*)out1 + (size_t)r * 256 + (cg - 256);
                    *reinterpret_cast<bf16x8*>(dst) = sv;
                } else if constexpr (MODE == M_ATTN){
                    if (cg < 256){
                        size_t o1 = (size_t)r * 256 + cg;
                        bf16x8 xv = *reinterpret_cast<const bf16x8*>((const unsigned short*)add + o1);
                        *reinterpret_cast<bf16x8*>((unsigned short*)out0 + o1) = add_bf8(sv, xv, 1.0f);
                    } else {
                        size_t o2 = (size_t)r * 128 + (cg - 256);
                        bf16x8 cv = *reinterpret_cast<const bf16x8*>((const unsigned short*)bias + o2);
                        *reinterpret_cast<bf16x8*>((unsigned short*)out1 + o2) = add_bf8(sv, cv, -1.0f);
                    }
                } else {
                    *reinterpret_cast<bf16x8*>((unsigned short*)out0 + (size_t)r * O + cg) = sv;
                }
            }
        }
    }
}

extern "C" void kernel_launch(void* const* d_in, const int* in_sizes, int n_in,
                              void* d_out, int out_size, void* d_ws, size_t ws_size,
                              hipStream_t stream){
    const float* x     = (const float*)d_in[0];
    const float* cor   = (const float*)d_in[1];
    const float* q_w   = (const float*)d_in[2];
    const float* kv_w  = (const float*)d_in[3];
    const float* cor_w = (const float*)d_in[4];
    const float* kln_w = (const float*)d_in[5];
    const float* kln_b = (const float*)d_in[6];
    const float* vln_w = (const float*)d_in[7];
    const float* vln_b = (const float*)d_in[8];
    const float* corln_w = (const float*)d_in[9];
    const float* corln_b = (const float*)d_in[10];
    const float* op1_w = (const float*)d_in[11];
    const float* op1_b = (const float*)d_in[12];
    const float* op2_w = (const float*)d_in[13];
    const float* op2_b = (const float*)d_in[14];
    const float* om1_w = (const float*)d_in[15];
    const float* om1_b = (const float*)d_in[16];
    const float* om2_w = (const float*)d_in[17];
    const float* om2_b = (const float*)d_in[18];
    const float* n1_w  = (const float*)d_in[19];
    const float* n1_b  = (const float*)d_in[20];
    const float* n2_w  = (const float*)d_in[21];
    const float* n2_b  = (const float*)d_in[22];
    const float* fc1_w = (const float*)d_in[23];
    const float* fc1_b = (const float*)d_in[24];
    const float* dw_w  = (const float*)d_in[25];
    const float* dw_b  = (const float*)d_in[26];
    const float* fc2_w = (const float*)d_in[27];
    const float* fc2_b = (const float*)d_in[28];

    // ---- workspace layout (bf16 elements unless noted) ----
    unsigned short* XN  = (unsigned short*)d_ws;           // NTOK*256
    unsigned short* Qb  = XN  + (size_t)NTOK * 256;
    unsigned short* Kb  = Qb  + (size_t)NTOK * 256;
    unsigned short* Vb  = Kb  + (size_t)NTOK * 256;
    unsigned short* CEF = Vb  + (size_t)NTOK * 256;        // NTOK*128
    unsigned short* CE  = CEF + (size_t)NTOK * 128;
    float* KTV = (float*)(CE + (size_t)NTOK * 128);        // 32768 f32
    float* KTC = KTV + 32768;                              // 16384 f32
    unsigned short* WTC = (unsigned short*)(KTC + 16384);  // 4*384*256 bf16
    unsigned short* Wb  = WTC + 4 * 384 * 256;             // 753664 bf16 weights
    unsigned short* H2  = Wb + 753664;                     // NTOK*768
    // overlays (disjoint live ranges):
    unsigned short* T1 = Vb;      // attn out, consumed by op1
    unsigned short* T2 = Kb;      // op1 out, consumed by op2
    unsigned short* Y  = Vb;      // fused op2+LN out (Vb dead after op1)
    unsigned short* TM = CE;      // dm, consumed by motion_kernel
    unsigned short* H1 = XN;      // spans XN+Qb+Kb = NTOK*768; fc1 reads Vb (disjoint)
    float* xout = (float*)d_out;
    float* mout = xout + (size_t)NTOK * 256;

    unsigned short* w_kv  = Wb + 65536;
    unsigned short* w_op1 = Wb + 196608;
    unsigned short* w_op2 = Wb + 262144;
    unsigned short* w_om1 = Wb + 327680;
    unsigned short* w_om2 = Wb + 344064;
    unsigned short* w_fc1 = Wb + 360448;
    unsigned short* w_fc2 = Wb + 557056;

    // 0. weights -> bf16
    wconv_kernel<<<736, 256, 0, stream>>>(q_w, kv_w, op1_w, op2_w, om1_w, om2_w, fc1_w, fc2_w, Wb);
    // 1. xn = std_ln(x, norm1)
    stdln_kernel<false><<<2048, 256, 0, stream>>>(x, n1_w, n1_b, XN);
    // 2. kv = xr @ kv_w.T (swapped rows), split K,V — WN=8 full width
    mgemm<M_KV, true, 256, 512, 8, 2><<<dim3(512, 1), 1024, 0, stream>>>(XN, w_kv, nullptr, nullptr, nullptr, nullptr, Kb, Vb);
    // 3. ce_flat
    ce_kernel<<<2048, 256, 0, stream>>>(cor, cor_w, CEF);
    // 4. zero accumulators
    hipMemsetAsync(KTV, 0, (32768 + 16384) * sizeof(float), stream);
    // 5. fused LN + ktv + ktc (register-tiled)
    ktvc_kernel<<<dim3(32, 32), 256, 0, stream>>>(Kb, Vb, CEF, kln_w, kln_b, vln_w, vln_b,
                                                  corln_w, corln_b, KTV, KTC);
    // 6. combined attention weights WTC[b] = q_w^T · blockdiag(ktv|ktc)
    wcomb_kernel<<<dim3(384, 4), 256, 0, stream>>>(q_w, KTV, KTC, WTC);
    // 7. [t | dm] = xn @ WTC[b] (+xn | -ce_flat) — WN=6 full width
    mgemm<M_ATTN, false, 256, 384, 6, 2><<<dim3(512, 1), 768, 0, stream>>>(XN, WTC, (const float*)CEF, XN, nullptr, nullptr, T1, TM);
    // 8. hidden = gelu(t @ op1.T + b) — WN=4
    mgemm<M_BIAS_GELU, false, 256, 256, 4, 2><<<dim3(512, 1), 512, 0, stream>>>(T1, w_op1, op1_b, nullptr, nullptr, nullptr, T2, nullptr);
    // 9. Y = LN2((hidden @ op2.T + b) + 2*xn) — fused op2+LN, WN=4 full width; Y=Vb
    mgemm<M_ADD2LN, false, 256, 256, 4, 2><<<dim3(512, 1), 512, 0, stream>>>(T2, w_op2, op2_b, XN, n2_w, n2_b, Y, nullptr);
    // 10. motion = gelu(dm @ om1.T + b1) @ om2.T + b2 -> output 1 (fused, LDS-resident mh)
    motion_kernel<<<512, 256, 0, stream>>>(TM, w_om1, om1_b, w_om2, om2_b, mout);
    // 11. h1 = y @ fc1.T + b (bf16) — WN=6, y=2; H1 = XN-span overlay (L3-warm)
    mgemm<M_BIAS_BF16, false, 256, 768, 6, 2><<<dim3(512, 2), 768, 0, stream>>>(Y, w_fc1, fc1_b, nullptr, nullptr, nullptr, H1, nullptr);
    // 12. depthwise conv + bias + gelu (y-banded, 16-col chunks, 1024 blocks)
    dwconv_kernel<<<1024, 192, 0, stream>>>(H1, dw_w, dw_b, H2);
    // 13. x_out = h2 @ fc2.T + b + x -> output 0 (fp32) — WM=1 M-split: 64-row tiles, 1024 blocks, 4/CU
    mgemm<M_BIAS_ADDX, false, 768, 256, 4, 1><<<dim3(1024, 1), 256, 0, stream>>>(H2, w_fc2, fc2_b, x, nullptr, nullptr, xout, nullptr);
}

// Round 18
// 403.551 us; speedup vs baseline: 1.0536x; 1.0536x over previous
//
#include <hip/hip_runtime.h>
#include <hip/hip_bf16.h>

#define NTOK 65536      // 4 * 16384 tokens

typedef __attribute__((ext_vector_type(4))) float f32x4;
typedef __attribute__((ext_vector_type(8))) short bf16x8;

__device__ __forceinline__ float gelu_f(float x){
    float z = -2.30234438f * fmaf(0.044715f * x * x, x, x);
    float e = exp2f(z);
    return x * __builtin_amdgcn_rcpf(1.0f + e);
}
__device__ __forceinline__ float bf2f(unsigned short u){
    union { unsigned int i; float f; } w; w.i = ((unsigned int)u) << 16; return w.f;
}
__device__ __forceinline__ unsigned short f2bf(float f){
    __hip_bfloat16 h = __float2bfloat16(f);
    return *reinterpret_cast<unsigned short*>(&h);
}
__device__ __forceinline__ bf16x8 add_bf8(bf16x8 s, bf16x8 o, float k){
    bf16x8 r;
    #pragma unroll
    for (int i = 0; i < 8; i++)
        r[i] = (short)f2bf(fmaf(k, bf2f((unsigned short)o[i]), bf2f((unsigned short)s[i])));
    return r;
}

// ---------- weight fp32 -> bf16 conversion into contiguous Wb ----------
__global__ __launch_bounds__(256) void wconv_kernel(const float* __restrict__ q_w, const float* __restrict__ kv_w,
                                                    const float* __restrict__ op1_w, const float* __restrict__ op2_w,
                                                    const float* __restrict__ om1_w, const float* __restrict__ om2_w,
                                                    const float* __restrict__ fc1_w, const float* __restrict__ fc2_w,
                                                    unsigned short* __restrict__ Wb){
    size_t e = ((size_t)blockIdx.x * 256 + threadIdx.x) * 4;
    if (e >= 753664) return;
    const float* src; size_t off;
    if      (e <  65536){ src = q_w;   off = 0; }
    else if (e < 196608){ src = kv_w;  off = 65536; }
    else if (e < 262144){ src = op1_w; off = 196608; }
    else if (e < 327680){ src = op2_w; off = 262144; }
    else if (e < 344064){ src = om1_w; off = 327680; }
    else if (e < 360448){ src = om2_w; off = 344064; }
    else if (e < 557056){ src = fc1_w; off = 360448; }
    else                { src = fc2_w; off = 557056; }
    float4 v = *reinterpret_cast<const float4*>(src + (e - off));
    ushort4 o; o.x = f2bf(v.x); o.y = f2bf(v.y); o.z = f2bf(v.z); o.w = f2bf(v.w);
    *reinterpret_cast<ushort4*>(Wb + e) = o;
}

// ---------- std LayerNorm over 256 -> bf16 out; wave-per-token, 8 tokens/wave ----------
template<bool BF16IN>
__global__ __launch_bounds__(256) void stdln_kernel(const void* __restrict__ Xp,
                                                    const float* __restrict__ w,
                                                    const float* __restrict__ b,
                                                    unsigned short* __restrict__ out){
    int wv = threadIdx.x >> 6, lane = threadIdx.x & 63;
    int tok0 = (blockIdx.x * 4 + wv) * 8;
    int c0 = lane * 4;
    float4 w4 = *reinterpret_cast<const float4*>(w + c0);
    float4 b4 = *reinterpret_cast<const float4*>(b + c0);
    #pragma unroll 2
    for (int j = 0; j < 8; j++){
        size_t base = (size_t)(tok0 + j) * 256 + c0;
        float v[4];
        if constexpr (BF16IN){
            ushort4 u = *reinterpret_cast<const ushort4*>((const unsigned short*)Xp + base);
            v[0] = bf2f(u.x); v[1] = bf2f(u.y); v[2] = bf2f(u.z); v[3] = bf2f(u.w);
        } else {
            float4 f = *reinterpret_cast<const float4*>((const float*)Xp + base);
            v[0] = f.x; v[1] = f.y; v[2] = f.z; v[3] = f.w;
        }
        float s = v[0] + v[1] + v[2] + v[3];
        #pragma unroll
        for (int m = 1; m < 64; m <<= 1) s += __shfl_xor(s, m, 64);
        float mean = s * (1.0f / 256.0f);
        float ss = 0;
        #pragma unroll
        for (int k = 0; k < 4; k++){ v[k] -= mean; ss = fmaf(v[k], v[k], ss); }
        #pragma unroll
        for (int m = 1; m < 64; m <<= 1) ss += __shfl_xor(ss, m, 64);
        float inv = rsqrtf(ss * (1.0f / 256.0f) + 1e-5f);
        ushort4 o;
        o.x = f2bf(w4.x * v[0] * inv + b4.x);
        o.y = f2bf(w4.y * v[1] * inv + b4.y);
        o.z = f2bf(w4.z * v[2] * inv + b4.z);
        o.w = f2bf(w4.w * v[3] * inv + b4.w);
        *reinterpret_cast<ushort4*>(out + base) = o;
    }
}

// ---------- ce_flat = cor @ cor_w.T (K=2), token-blocked ----------
__global__ __launch_bounds__(256) void ce_kernel(const float* __restrict__ cor,
                                                 const float* __restrict__ cor_w,
                                                 unsigned short* __restrict__ CEF){
    int m = threadIdx.x & 127, half = threadIdx.x >> 7;
    float w0 = cor_w[m * 2 + 0], w1 = cor_w[m * 2 + 1];
    #pragma unroll 4
    for (int it = 0; it < 16; it++){
        int tok = blockIdx.x * 32 + it * 2 + half;
        float c0 = cor[(size_t)tok * 2 + 0];
        float c1 = cor[(size_t)tok * 2 + 1];
        CEF[(size_t)tok * 128 + m] = f2bf(c0 * w0 + c1 * w1);
    }
}

// ---------- fused: on-the-fly custom LN of K,V,CE + ktv & ktc reductions ----------
__global__ __launch_bounds__(256) void ktvc_kernel(const unsigned short* __restrict__ Kb,
                                                   const unsigned short* __restrict__ Vb,
                                                   const unsigned short* __restrict__ CEF,
                                                   const float* __restrict__ kw, const float* __restrict__ kbb,
                                                   const float* __restrict__ vw, const float* __restrict__ vbb,
                                                   const float* __restrict__ cw, const float* __restrict__ cbb,
                                                   float* __restrict__ KTV, float* __restrict__ KTC){
    int bh = blockIdx.x, b = bh >> 3, h = bh & 7;
    __shared__ float Ks[64][36];
    __shared__ float Vs[64][36];
    __shared__ float Cs[64][20];
    __shared__ float P[2][64][24];
    int t = threadIdx.x;
    int lr = t >> 2, lq = t & 3;
    int g = t >> 6, tl = t & 63;
    int d0 = (tl >> 3) * 4, e0 = (tl & 7) * 4, e0c = (tl & 7) * 2;
    float kwr[8], kbr[8], vwr[8], vbr[8], cwr[4], cbr[4];
    #pragma unroll
    for (int j = 0; j < 8; j++){
        kwr[j] = kw[h * 32 + lq * 8 + j]; kbr[j] = kbb[h * 32 + lq * 8 + j];
        vwr[j] = vw[h * 32 + lq * 8 + j]; vbr[j] = vbb[h * 32 + lq * 8 + j];
    }
    #pragma unroll
    for (int j = 0; j < 4; j++){
        cwr[j] = cw[h * 16 + lq * 4 + j]; cbr[j] = cbb[h * 16 + lq * 4 + j];
    }
    float akv[4][4] = {};
    float akc[4][2] = {};
    size_t base = ((size_t)b << 14) + (size_t)blockIdx.y * 512;
    for (int n0 = 0; n0 < 512; n0 += 64){
        size_t rowi = base + n0 + lr;
        const ushort4* kp = reinterpret_cast<const ushort4*>(Kb + rowi * 256 + h * 32 + lq * 8);
        ushort4 ka = kp[0], kc = kp[1];
        const ushort4* vp = reinterpret_cast<const ushort4*>(Vb + rowi * 256 + h * 32 + lq * 8);
        ushort4 va = vp[0], vc = vp[1];
        ushort4 ca = *reinterpret_cast<const ushort4*>(CEF + rowi * 128 + h * 16 + lq * 4);
        float kvv[8] = { bf2f(ka.x), bf2f(ka.y), bf2f(ka.z), bf2f(ka.w),
                         bf2f(kc.x), bf2f(kc.y), bf2f(kc.z), bf2f(kc.w) };
        float vvv[8] = { bf2f(va.x), bf2f(va.y), bf2f(va.z), bf2f(va.w),
                         bf2f(vc.x), bf2f(vc.y), bf2f(vc.z), bf2f(vc.w) };
        float cvv[4] = { bf2f(ca.x), bf2f(ca.y), bf2f(ca.z), bf2f(ca.w) };
        float s = 0;
        #pragma unroll
        for (int j = 0; j < 8; j++) s += kvv[j];
        s += __shfl_xor(s, 1, 64); s += __shfl_xor(s, 2, 64);
        float mean = s * (1.0f / 32.0f);
        float ss = 0;
        #pragma unroll
        for (int j = 0; j < 8; j++){ kvv[j] -= mean; ss = fmaf(kvv[j], kvv[j], ss); }
        ss += __shfl_xor(ss, 1, 64); ss += __shfl_xor(ss, 2, 64);
        float inv = 1.0f / (sqrtf(ss * (1.0f / 31.0f)) + 1e-5f);
        #pragma unroll
        for (int j = 0; j < 8; j++) kvv[j] = fmaf(kwr[j] * kvv[j], inv, kbr[j]);
        s = 0;
        #pragma unroll
        for (int j = 0; j < 8; j++) s += vvv[j];
        s += __shfl_xor(s, 1, 64); s += __shfl_xor(s, 2, 64);
        mean = s * (1.0f / 32.0f);
        ss = 0;
        #pragma unroll
        for (int j = 0; j < 8; j++){ vvv[j] -= mean; ss = fmaf(vvv[j], vvv[j], ss); }
        ss += __shfl_xor(ss, 1, 64); ss += __shfl_xor(ss, 2, 64);
        inv = 1.0f / (sqrtf(ss * (1.0f / 31.0f)) + 1e-5f);
        #pragma unroll
        for (int j = 0; j < 8; j++) vvv[j] = fmaf(vwr[j] * vvv[j], inv, vbr[j]);
        s = 0;
        #pragma unroll
        for (int j = 0; j < 4; j++) s += cvv[j];
        s += __shfl_xor(s, 1, 64); s += __shfl_xor(s, 2, 64);
        mean = s * (1.0f / 16.0f);
        ss = 0;
        #pragma unroll
        for (int j = 0; j < 4; j++){ cvv[j] -= mean; ss = fmaf(cvv[j], cvv[j], ss); }
        ss += __shfl_xor(ss, 1, 64); ss += __shfl_xor(ss, 2, 64);
        inv = 1.0f / (sqrtf(ss * (1.0f / 15.0f)) + 1e-5f);
        #pragma unroll
        for (int j = 0; j < 4; j++) cvv[j] = fmaf(cwr[j] * cvv[j], inv, cbr[j]);
        __syncthreads();
        #pragma unroll
        for (int j = 0; j < 8; j++){ Ks[lr][lq * 8 + j] = kvv[j]; Vs[lr][lq * 8 + j] = vvv[j]; }
        #pragma unroll
        for (int j = 0; j < 4; j++) Cs[lr][lq * 4 + j] = cvv[j];
        __syncthreads();
        #pragma unroll 4
        for (int i = 0; i < 16; i++){
            int n = g * 16 + i;
            float4 k4 = *reinterpret_cast<const float4*>(&Ks[n][d0]);
            float4 v4 = *reinterpret_cast<const float4*>(&Vs[n][e0]);
            float2 c2 = *reinterpret_cast<const float2*>(&Cs[n][e0c]);
            float kk[4] = { k4.x, k4.y, k4.z, k4.w };
            float vv[4] = { v4.x, v4.y, v4.z, v4.w };
            #pragma unroll
            for (int a = 0; a < 4; a++){
                akv[a][0] = fmaf(kk[a], vv[0], akv[a][0]);
                akv[a][1] = fmaf(kk[a], vv[1], akv[a][1]);
                akv[a][2] = fmaf(kk[a], vv[2], akv[a][2]);
                akv[a][3] = fmaf(kk[a], vv[3], akv[a][3]);
                akc[a][0] = fmaf(kk[a], c2.x, akc[a][0]);
                akc[a][1] = fmaf(kk[a], c2.y, akc[a][1]);
            }
        }
    }
    __syncthreads();
    if (g >= 2){
        float* p = &P[g - 2][tl][0];
        #pragma unroll
        for (int a = 0; a < 4; a++){
            #pragma unroll
            for (int e = 0; e < 4; e++) p[a * 4 + e] = akv[a][e];
            p[16 + a * 2 + 0] = akc[a][0];
            p[16 + a * 2 + 1] = akc[a][1];
        }
    }
    __syncthreads();
    if (g < 2){
        const float* p = &P[g][tl][0];
        #pragma unroll
        for (int a = 0; a < 4; a++){
            #pragma unroll
            for (int e = 0; e < 4; e++) akv[a][e] += p[a * 4 + e];
            akc[a][0] += p[16 + a * 2 + 0];
            akc[a][1] += p[16 + a * 2 + 1];
        }
    }
    __syncthreads();
    if (g == 1){
        float* p = &P[0][tl][0];
        #pragma unroll
        for (int a = 0; a < 4; a++){
            #pragma unroll
            for (int e = 0; e < 4; e++) p[a * 4 + e] = akv[a][e];
            p[16 + a * 2 + 0] = akc[a][0];
            p[16 + a * 2 + 1] = akc[a][1];
        }
    }
    __syncthreads();
    if (g == 0){
        const float* p = &P[0][tl][0];
        const float sc = 1.0f / 16384.0f;
        float* o = KTV + (size_t)bh * 1024;
        float* o2 = KTC + (size_t)bh * 512;
        #pragma unroll
        for (int a = 0; a < 4; a++){
            #pragma unroll
            for (int e = 0; e < 4; e++)
                atomicAdd(&o[(d0 + a) * 32 + e0 + e], (akv[a][e] + p[a * 4 + e]) * sc);
            atomicAdd(&o2[(d0 + a) * 16 + e0c + 0], (akc[a][0] + p[16 + a * 2 + 0]) * sc);
            atomicAdd(&o2[(d0 + a) * 16 + e0c + 1], (akc[a][1] + p[16 + a * 2 + 1]) * sc);
        }
    }
}

// ---------- combined attention weights ----------
__global__ __launch_bounds__(256) void wcomb_kernel(const float* __restrict__ q_w,
                                                    const float* __restrict__ KTV,
                                                    const float* __restrict__ KTC,
                                                    unsigned short* __restrict__ WTC){
    int c = blockIdx.x;
    int b = blockIdx.y;
    int i = threadIdx.x;
    __shared__ float coef[32];
    int h = (c < 256) ? (c >> 5) : ((c - 256) >> 4);
    if (i < 32){
        if (c < 256) coef[i] = KTV[(size_t)((b * 8 + h) << 10) + i * 32 + (c & 31)];
        else         coef[i] = KTC[(size_t)((b * 8 + h) << 9)  + i * 16 + ((c - 256) & 15)];
    }
    __syncthreads();
    float acc = 0;
    #pragma unroll
    for (int d = 0; d < 32; d++) acc = fmaf(q_w[(size_t)(h * 32 + d) * 256 + i], coef[d], acc);
    WTC[((size_t)b * 384 + c) * 256 + i] = f2bf(acc);
}

// ---------- fused motion MLP: mout = gelu(dm @ om1.T + b1) @ om2.T + b2 ----------
__global__ __launch_bounds__(256) void motion_kernel(const unsigned short* __restrict__ TM,
                                                     const unsigned short* __restrict__ w1,
                                                     const float* __restrict__ b1,
                                                     const unsigned short* __restrict__ w2,
                                                     const float* __restrict__ b2,
                                                     float* __restrict__ mout){
    __shared__ __align__(16) unsigned short SMEM[32768];
    unsigned short* STG = SMEM;
    unsigned short* MH  = SMEM + 16384;
    const int t = threadIdx.x;
    const int lane = t & 63, wid = t >> 6;
    const int wm = wid & 1, wn = wid >> 1;
    const int row0 = blockIdx.x * 128;
    const int lr = lane >> 2;
    const int ls = lane & 3;
    const int kq = lane >> 4;
    const int rr = lane & 15;
    f32x4 acc[4][4];
    #pragma unroll
    for (int i = 0; i < 4; i++)
        #pragma unroll
        for (int j = 0; j < 4; j++){ f32x4 z = {0.f, 0.f, 0.f, 0.f}; acc[i][j] = z; }

    auto STAGE1 = [&](int buf, int kb){
        #pragma unroll
        for (int c = wid; c < 16; c += 4){
            int r16 = (c < 8) ? c : (c - 8);
            int row = r16 * 16 + lr;
            int ko = ls ^ ((row >> 1) & 3);
            if (c < 8){
                __builtin_amdgcn_global_load_lds(
                    (const __attribute__((address_space(1))) unsigned int*)(TM + (size_t)(row0 + row) * 128 + kb + ko * 8),
                    (__attribute__((address_space(3))) unsigned int*)(STG + buf * 4096 + r16 * 512),
                    16, 0, 0);
            } else {
                __builtin_amdgcn_global_load_lds(
                    (const __attribute__((address_space(1))) unsigned int*)(w1 + (size_t)row * 128 + kb + ko * 8),
                    (__attribute__((address_space(3))) unsigned int*)(STG + 8192 + buf * 4096 + r16 * 512),
                    16, 0, 0);
            }
        }
    };

    STAGE1(0, 0);
    asm volatile("s_waitcnt vmcnt(0)" ::: "memory");
    __builtin_amdgcn_s_barrier();
    #pragma unroll 1
    for (int tt = 0; tt < 4; tt++){
        int cur = tt & 1;
        if (tt + 1 < 4) STAGE1(cur ^ 1, (tt + 1) * 32);
        bf16x8 af[4], bfr[4];
        #pragma unroll
        for (int m = 0; m < 4; m++){
            int row = wm * 64 + m * 16 + rr;
            int s = kq ^ ((row >> 1) & 3);
            af[m] = *reinterpret_cast<const bf16x8*>(STG + cur * 4096 + row * 32 + s * 8);
        }
        #pragma unroll
        for (int n = 0; n < 4; n++){
            int row = wn * 64 + n * 16 + rr;
            int s = kq ^ ((row >> 1) & 3);
            bfr[n] = *reinterpret_cast<const bf16x8*>(STG + 8192 + cur * 4096 + row * 32 + s * 8);
        }
        #pragma unroll
        for (int m = 0; m < 4; m++)
            #pragma unroll
            for (int n = 0; n < 4; n++)
                acc[m][n] = __builtin_amdgcn_mfma_f32_16x16x32_bf16(af[m], bfr[n], acc[m][n], 0, 0, 0);
        if (tt + 1 < 4){
            asm volatile("s_waitcnt vmcnt(0)" ::: "memory");
            __builtin_amdgcn_s_barrier();
        }
    }

    __builtin_amdgcn_s_barrier();
    #pragma unroll
    for (int c = wid; c < 32; c += 4){
        int kt = c >> 3, r16 = c & 7;
        int row = r16 * 16 + lr;
        int ko = ls ^ ((row >> 1) & 3);
        __builtin_amdgcn_global_load_lds(
            (const __attribute__((address_space(1))) unsigned int*)(w2 + (size_t)row * 128 + kt * 32 + ko * 8),
            (__attribute__((address_space(3))) unsigned int*)(STG + kt * 4096 + r16 * 512),
            16, 0, 0);
    }
    #pragma unroll
    for (int m = 0; m < 4; m++){
        #pragma unroll
        for (int n = 0; n < 4; n++){
            int col = wn * 64 + n * 16 + rr;
            float bb = b1[col];
            int kt = col >> 5, ck = col & 31;
            #pragma unroll
            for (int j = 0; j < 4; j++){
                int r = wm * 64 + m * 16 + kq * 4 + j;
                int ps = (ck >> 3) ^ ((r >> 1) & 3);
                MH[kt * 4096 + r * 32 + ps * 8 + (ck & 7)] = f2bf(gelu_f(acc[m][n][j] + bb));
            }
        }
    }
    asm volatile("s_waitcnt vmcnt(0)" ::: "memory");
    __syncthreads();

    f32x4 acc2[4][4];
    #pragma unroll
    for (int i = 0; i < 4; i++)
        #pragma unroll
        for (int j = 0; j < 4; j++){ f32x4 z = {0.f, 0.f, 0.f, 0.f}; acc2[i][j] = z; }
    #pragma unroll
    for (int tt = 0; tt < 4; tt++){
        bf16x8 af[4], bfr[4];
        #pragma unroll
        for (int m = 0; m < 4; m++){
            int row = wm * 64 + m * 16 + rr;
            int s = kq ^ ((row >> 1) & 3);
            af[m] = *reinterpret_cast<const bf16x8*>(MH + tt * 4096 + row * 32 + s * 8);
        }
        #pragma unroll
        for (int n = 0; n < 4; n++){
            int row = wn * 64 + n * 16 + rr;
            int s = kq ^ ((row >> 1) & 3);
            bfr[n] = *reinterpret_cast<const bf16x8*>(STG + tt * 4096 + row * 32 + s * 8);
        }
        #pragma unroll
        for (int m = 0; m < 4; m++)
            #pragma unroll
            for (int n = 0; n < 4; n++)
                acc2[m][n] = __builtin_amdgcn_mfma_f32_16x16x32_bf16(af[m], bfr[n], acc2[m][n], 0, 0, 0);
    }

    __syncthreads();
    float* scrf = (float*)MH + (size_t)wid * 1088;
    const int rloc = lane >> 2;
    const int cs = (lane & 3) * 16;
    #pragma unroll
    for (int m = 0; m < 4; m++){
        #pragma unroll
        for (int n = 0; n < 4; n++){
            int col = wn * 64 + n * 16 + rr;
            float bb = b2[col];
            #pragma unroll
            for (int j = 0; j < 4; j++)
                scrf[(kq * 4 + j) * 68 + n * 16 + rr] = acc2[m][n][j] + bb;
        }
        int r = row0 + wm * 64 + m * 16 + rloc;
        int colb = wn * 64 + cs;
        #pragma unroll
        for (int q = 0; q < 4; q++){
            float4 vv = *reinterpret_cast<const float4*>(&scrf[rloc * 68 + cs + q * 4]);
            *reinterpret_cast<float4*>(&mout[(size_t)r * 128 + colb + q * 4]) = vv;
        }
    }
}

// ---------- depthwise 3x3 conv (SAME) + bias + gelu, y-banded (4 rows) x 16-col chunks ----------
__global__ __launch_bounds__(192) void dwconv_kernel(const unsigned short* __restrict__ H1,
                                                     const float* __restrict__ dww,
                                                     const float* __restrict__ dwb,
                                                     unsigned short* __restrict__ H2){
    int blk = blockIdx.x;
    int xq = blk & 7;
    int yb = (blk >> 3) & 31;
    int bb = blk >> 8;
    int y0 = yb * 4, x0 = xq * 16;
    int ch = threadIdx.x * 4;
    float w[9][4];
    #pragma unroll
    for (int k = 0; k < 9; k++)
        #pragma unroll
        for (int j = 0; j < 4; j++) w[k][j] = dww[(ch + j) * 9 + k];
    float bias[4] = { dwb[ch], dwb[ch+1], dwb[ch+2], dwb[ch+3] };
    size_t rb[6]; bool rv[6];
    #pragma unroll
    for (int r = 0; r < 6; r++){
        int yr = y0 - 1 + r;
        rv[r] = ((unsigned)yr <= 127u);
        int yc = yr < 0 ? 0 : (yr > 127 ? 127 : yr);
        rb[r] = ((size_t)((bb << 14) + (yc << 7))) * 768 + ch;
    }
    size_t ob[4];
    #pragma unroll
    for (int j = 0; j < 4; j++) ob[j] = ((size_t)((bb << 14) + ((y0 + j) << 7))) * 768 + ch;

    ushort4 cA[6], cB[6], cC[6], cD[6];
    const ushort4 Z = {0, 0, 0, 0};
    #define LOADR(DST, XX) do {                                               \
        int _x = (XX);                                                        \
        bool xv = ((unsigned)_x <= 127u);                                     \
        _Pragma("unroll")                                                     \
        for (int r = 0; r < 6; r++)                                           \
            DST[r] = (xv && rv[r]) ? *reinterpret_cast<const ushort4*>(H1 + rb[r] + (size_t)_x * 768) : Z; \
    } while (0)

    #define EMITB(SA, SB, SC, XX) do {                                        \
        _Pragma("unroll")                                                     \
        for (int j = 0; j < 4; j++){                                          \
            float acc[4];                                                     \
            _Pragma("unroll")                                                 \
            for (int q = 0; q < 4; q++) acc[q] = bias[q];                     \
            _Pragma("unroll")                                                 \
            for (int rr2 = 0; rr2 < 3; rr2++){                                \
                int ri = j + rr2;                                             \
                float a0=bf2f(SA[ri].x),a1=bf2f(SA[ri].y),a2=bf2f(SA[ri].z),a3=bf2f(SA[ri].w); \
                float b0=bf2f(SB[ri].x),b1=bf2f(SB[ri].y),b2=bf2f(SB[ri].z),b3=bf2f(SB[ri].w); \
                float c0=bf2f(SC[ri].x),c1=bf2f(SC[ri].y),c2=bf2f(SC[ri].z),c3=bf2f(SC[ri].w); \
                acc[0]=fmaf(a0,w[rr2*3+0][0],acc[0]); acc[0]=fmaf(b0,w[rr2*3+1][0],acc[0]); acc[0]=fmaf(c0,w[rr2*3+2][0],acc[0]); \
                acc[1]=fmaf(a1,w[rr2*3+0][1],acc[1]); acc[1]=fmaf(b1,w[rr2*3+1][1],acc[1]); acc[1]=fmaf(c1,w[rr2*3+2][1],acc[1]); \
                acc[2]=fmaf(a2,w[rr2*3+0][2],acc[2]); acc[2]=fmaf(b2,w[rr2*3+1][2],acc[2]); acc[2]=fmaf(c2,w[rr2*3+2][2],acc[2]); \
                acc[3]=fmaf(a3,w[rr2*3+0][3],acc[3]); acc[3]=fmaf(b3,w[rr2*3+1][3],acc[3]); acc[3]=fmaf(c3,w[rr2*3+2][3],acc[3]); \
            }                                                                 \
            ushort4 o;                                                        \
            o.x = f2bf(gelu_f(acc[0])); o.y = f2bf(gelu_f(acc[1]));           \
            o.z = f2bf(gelu_f(acc[2])); o.w = f2bf(gelu_f(acc[3]));           \
            *reinterpret_cast<ushort4*>(H2 + ob[j] + (size_t)(XX) * 768) = o; \
        }                                                                     \
    } while (0)

    LOADR(cD, x0 - 1);
    LOADR(cA, x0);
    LOADR(cB, x0 + 1);
    LOADR(cC, x0 + 2);
    #pragma unroll 1
    for (int g = 0; g < 4; g++){
        int x = x0 + g * 4;
        EMITB(cD, cA, cB, x);     LOADR(cD, x + 3);
        EMITB(cA, cB, cC, x + 1); LOADR(cA, x + 4);
        EMITB(cB, cC, cD, x + 2); LOADR(cB, x + 5);
        EMITB(cC, cD, cA, x + 3); LOADR(cC, x + 6);
    }
    #undef LOADR
    #undef EMITB
}

// ---------- bf16 MFMA GEMM, wide-N, drain pipeline (r9/r16 config), coalesced repack epilogue ----------
#define M_KV        1
#define M_BIAS_GELU 2
#define M_BIAS_BF16 5
#define M_BIAS_ADDX 6
#define M_ATTN      7
#define M_ADD2LN    8

template<int MODE, bool SWAP, int K, int O, int WN>
__global__ __launch_bounds__(128 * WN) void mgemm(const unsigned short* __restrict__ A,
                                                  const unsigned short* __restrict__ Wp,
                                                  const float* __restrict__ bias,
                                                  const void* __restrict__ add,
                                                  const float* __restrict__ nw,
                                                  const float* __restrict__ nb,
                                                  void* __restrict__ out0,
                                                  void* __restrict__ out1){
    constexpr int WAVES = 2 * WN;
    constexpr int BN = 64 * WN;
    constexpr int CH = 8 + 4 * WN;
    constexpr int NT = K / 32;
    constexpr bool F32OUT = (MODE == M_BIAS_ADDX);
    __shared__ __align__(16) unsigned short SMEM[2 * 128 * 32 + 2 * BN * 32];
    unsigned short* As0 = SMEM;
    unsigned short* Bs0 = SMEM + 2 * 128 * 32;
    const int t = threadIdx.x;
    const int lane = t & 63, wid = t >> 6;
    const int wm = wid & 1, wn = wid >> 1;
    const int row0 = blockIdx.x * 128;
    const int colB = blockIdx.y * BN;
    const unsigned short* W = Wp;
    if constexpr (MODE == M_ATTN) W += (size_t)(row0 >> 14) * (384 * 256);
    f32x4 acc[4][4];
    #pragma unroll
    for (int i = 0; i < 4; i++)
        #pragma unroll
        for (int j = 0; j < 4; j++){ f32x4 z = {0.f, 0.f, 0.f, 0.f}; acc[i][j] = z; }

    const int lr = lane >> 2;
    const int ls = lane & 3;
    const int kq = lane >> 4;
    const int rr = lane & 15;

    auto STAGE = [&](int buf, int kb){
        #pragma unroll
        for (int c = wid; c < CH; c += WAVES){
            int r16 = (c < 8) ? c : (c - 8);
            int row = r16 * 16 + lr;
            int ko = ls ^ ((row >> 1) & 3);
            if (c < 8){
                int ga = row0 + row;
                if (SWAP) ga ^= 32768;
                __builtin_amdgcn_global_load_lds(
                    (const __attribute__((address_space(1))) unsigned int*)(A + (size_t)ga * K + kb + ko * 8),
                    (__attribute__((address_space(3))) unsigned int*)(As0 + buf * 4096 + r16 * 512),
                    16, 0, 0);
            } else {
                int gc = colB + row;
                __builtin_amdgcn_global_load_lds(
                    (const __attribute__((address_space(1))) unsigned int*)(W + (size_t)gc * K + kb + ko * 8),
                    (__attribute__((address_space(3))) unsigned int*)(Bs0 + buf * (BN * 32) + r16 * 512),
                    16, 0, 0);
            }
        }
    };

    STAGE(0, 0);
    asm volatile("s_waitcnt vmcnt(0)" ::: "memory");
    __builtin_amdgcn_s_barrier();
    #pragma unroll 1
    for (int tt = 0; tt < NT; tt++){
        int cur = tt & 1;
        if (tt + 1 < NT) STAGE(cur ^ 1, (tt + 1) * 32);
        bf16x8 af[4], bfr[4];
        #pragma unroll
        for (int m = 0; m < 4; m++){
            int row = wm * 64 + m * 16 + rr;
            int s = kq ^ ((row >> 1) & 3);
            af[m] = *reinterpret_cast<const bf16x8*>(As0 + cur * 4096 + row * 32 + s * 8);
        }
        #pragma unroll
        for (int n = 0; n < 4; n++){
            int row = wn * 64 + n * 16 + rr;
            int s = kq ^ ((row >> 1) & 3);
            bfr[n] = *reinterpret_cast<const bf16x8*>(Bs0 + cur * (BN * 32) + row * 32 + s * 8);
        }
        #pragma unroll
        for (int m = 0; m < 4; m++)
            #pragma unroll
            for (int n = 0; n < 4; n++)
                acc[m][n] = __builtin_amdgcn_mfma_f32_16x16x32_bf16(af[m], bfr[n], acc[m][n], 0, 0, 0);
        if (tt + 1 < NT){
            asm volatile("s_waitcnt vmcnt(0)" ::: "memory");
            __builtin_amdgcn_s_barrier();
        }
    }

    // ---- epilogue ----
    __syncthreads();
    unsigned short* scr = SMEM + (size_t)wid * 2304;
    float* scrf = (float*)scr;
    const int rloc = lane >> 2;
    const int cs = (lane & 3) * 16;

    if constexpr (MODE == M_ADD2LN){
        float* rowS = (float*)(SMEM + 20480);   // [4][128] floats
        float* rowQ = rowS + 512;               // [4][128]
        #pragma unroll
        for (int m = 0; m < 4; m++){
            #pragma unroll
            for (int j = 0; j < 4; j++){
                int r = row0 + wm * 64 + m * 16 + kq * 4 + j;
                float s = 0, q = 0;
                #pragma unroll
                for (int n = 0; n < 4; n++){
                    int col = wn * 64 + n * 16 + rr;
                    float v = acc[m][n][j] + bias[col]
                            + 2.0f * bf2f(((const unsigned short*)add)[(size_t)r * 256 + col]);
                    acc[m][n][j] = v;
                    s += v; q = fmaf(v, v, q);
                }
                s += __shfl_xor(s, 1, 64); s += __shfl_xor(s, 2, 64);
                s += __shfl_xor(s, 4, 64); s += __shfl_xor(s, 8, 64);
                q += __shfl_xor(q, 1, 64); q += __shfl_xor(q, 2, 64);
                q += __shfl_xor(q, 4, 64); q += __shfl_xor(q, 8, 64);
                if (rr == 0){
                    int lrow = wm * 64 + m * 16 + kq * 4 + j;
                    rowS[wn * 128 + lrow] = s;
                    rowQ[wn * 128 + lrow] = q;
                }
            }
        }
        __syncthreads();
        #pragma unroll
        for (int m = 0; m < 4; m++){
            #pragma unroll
            for (int n = 0; n < 4; n++){
                int col = wn * 64 + n * 16 + rr;
                float w2 = nw[col], b2 = nb[col];
                #pragma unroll
                for (int j = 0; j < 4; j++){
                    int lrow = wm * 64 + m * 16 + kq * 4 + j;
                    float S = rowS[lrow] + rowS[128 + lrow] + rowS[256 + lrow] + rowS[384 + lrow];
                    float Q = rowQ[lrow] + rowQ[128 + lrow] + rowQ[256 + lrow] + rowQ[384 + lrow];
                    float mean = S * (1.0f / 256.0f);
                    float var = fmaxf(Q * (1.0f / 256.0f) - mean * mean, 0.0f);
                    float inv = rsqrtf(var + 1e-5f);
                    float y = w2 * (acc[m][n][j] - mean) * inv + b2;
                    scr[(kq * 4 + j) * 68 + n * 16 + rr] = f2bf(y);
                }
            }
            int r = row0 + wm * 64 + m * 16 + rloc;
            #pragma unroll
            for (int q = 0; q < 2; q++){
                bf16x8 sv = *reinterpret_cast<const bf16x8*>(&scr[rloc * 68 + cs + q * 8]);
                int cg = wn * 64 + cs + q * 8;
                *reinterpret_cast<bf16x8*>((unsigned short*)out0 + (size_t)r * O + cg) = sv;
            }
        }
        return;
    }

    #pragma unroll
    for (int m = 0; m < 4; m++){
        #pragma unroll
        for (int n = 0; n < 4; n++){
            int col = colB + wn * 64 + n * 16 + rr;
            #pragma unroll
            for (int j = 0; j < 4; j++){
                float v = acc[m][n][j];
                int si = (kq * 4 + j) * 68 + n * 16 + rr;
                if constexpr (MODE == M_KV)            scr[si] = f2bf(v);
                else if constexpr (MODE == M_BIAS_GELU) scr[si] = f2bf(gelu_f(v + bias[col]));
                else if constexpr (MODE == M_BIAS_BF16) scr[si] = f2bf(v + bias[col]);
                else if constexpr (MODE == M_ATTN)      scr[si] = f2bf(v);
                else if constexpr (MODE == M_BIAS_ADDX) scrf[si] = v + bias[col];
            }
        }
        int r = row0 + wm * 64 + m * 16 + rloc;
        int colb = colB + wn * 64 + cs;
        if constexpr (F32OUT){
            #pragma unroll
            for (int q = 0; q < 4; q++){
                float4 vv = *reinterpret_cast<const float4*>(&scrf[rloc * 68 + cs + q * 4]);
                size_t o = (size_t)r * O + colb + q * 4;
                float4 xa = *reinterpret_cast<const float4*>(&((const float*)add)[o]);
                vv.x += xa.x; vv.y += xa.y; vv.z += xa.z; vv.w += xa.w;
                *reinterpret_cast<float4*>(&((float*)out0)[o]) = vv;
            }
        } else {
            #pragma unroll
            for (int q = 0; q < 2; q++){
                bf16x8 sv = *reinterpret_cast<const bf16x8*>(&scr[rloc * 68 + cs + q * 8]);
                int cg = colb + q * 8;
                if constexpr (MODE == M_KV){
                    unsigned short* dst = (cg < 256)
                        ? (unsigned short*)out0 + (size_t)r * 256 + cg
                        : (unsigned short*)out1 + (size_t)r * 256 + (cg - 256);
                    *reinterpret_cast<bf16x8*>(dst) = sv;
                } else if constexpr (MODE == M_ATTN){
                    if (cg < 256){
                        size_t o1 = (size_t)r * 256 + cg;
                        bf16x8 xv = *reinterpret_cast<const bf16x8*>((const unsigned short*)add + o1);
                        *reinterpret_cast<bf16x8*>((unsigned short*)out0 + o1) = add_bf8(sv, xv, 1.0f);
                    } else {
                        size_t o2 = (size_t)r * 128 + (cg - 256);
                        bf16x8 cv = *reinterpret_cast<const bf16x8*>((const unsigned short*)bias + o2);
                        *reinterpret_cast<bf16x8*>((unsigned short*)out1 + o2) = add_bf8(sv, cv, -1.0f);
                    }
                } else {
                    *reinterpret_cast<bf16x8*>((unsigned short*)out0 + (size_t)r * O + cg) = sv;
                }
            }
        }
    }
}

extern "C" void kernel_launch(void* const* d_in, const int* in_sizes, int n_in,
                              void* d_out, int out_size, void* d_ws, size_t ws_size,
                              hipStream_t stream){
    const float* x     = (const float*)d_in[0];
    const float* cor   = (const float*)d_in[1];
    const float* q_w   = (const float*)d_in[2];
    const float* kv_w  = (const float*)d_in[3];
    const float* cor_w = (const float*)d_in[4];
    const float* kln_w = (const float*)d_in[5];
    const float* kln_b = (const float*)d_in[6];
    const float* vln_w = (const float*)d_in[7];
    const float* vln_b = (const float*)d_in[8];
    const float* corln_w = (const float*)d_in[9];
    const float* corln_b = (const float*)d_in[10];
    const float* op1_w = (const float*)d_in[11];
    const float* op1_b = (const float*)d_in[12];
    const float* op2_w = (const float*)d_in[13];
    const float* op2_b = (const float*)d_in[14];
    const float* om1_w = (const float*)d_in[15];
    const float* om1_b = (const float*)d_in[16];
    const float* om2_w = (const float*)d_in[17];
    const float* om2_b = (const float*)d_in[18];
    const float* n1_w  = (const float*)d_in[19];
    const float* n1_b  = (const float*)d_in[20];
    const float* n2_w  = (const float*)d_in[21];
    const float* n2_b  = (const float*)d_in[22];
    const float* fc1_w = (const float*)d_in[23];
    const float* fc1_b = (const float*)d_in[24];
    const float* dw_w  = (const float*)d_in[25];
    const float* dw_b  = (const float*)d_in[26];
    const float* fc2_w = (const float*)d_in[27];
    const float* fc2_b = (const float*)d_in[28];

    // ---- workspace layout (bf16 elements unless noted) ----
    unsigned short* XN  = (unsigned short*)d_ws;           // NTOK*256
    unsigned short* Qb  = XN  + (size_t)NTOK * 256;
    unsigned short* Kb  = Qb  + (size_t)NTOK * 256;
    unsigned short* Vb  = Kb  + (size_t)NTOK * 256;
    unsigned short* CEF = Vb  + (size_t)NTOK * 256;        // NTOK*128
    unsigned short* CE  = CEF + (size_t)NTOK * 128;
    float* KTV = (float*)(CE + (size_t)NTOK * 128);        // 32768 f32
    float* KTC = KTV + 32768;                              // 16384 f32
    unsigned short* WTC = (unsigned short*)(KTC + 16384);  // 4*384*256 bf16
    unsigned short* Wb  = WTC + 4 * 384 * 256;             // 753664 bf16 weights
    unsigned short* H2  = Wb + 753664;                     // NTOK*768
    // overlays (disjoint live ranges):
    unsigned short* T1 = Vb;      // attn out, consumed by op1
    unsigned short* T2 = Kb;      // op1 out, consumed by op2
    unsigned short* Y  = Vb;      // fused op2+LN out (Vb dead after op1)
    unsigned short* TM = CE;      // dm, consumed by motion_kernel
    unsigned short* H1 = XN;      // spans XN+Qb+Kb = NTOK*768; fc1 reads Vb (disjoint)
    float* xout = (float*)d_out;
    float* mout = xout + (size_t)NTOK * 256;

    unsigned short* w_kv  = Wb + 65536;
    unsigned short* w_op1 = Wb + 196608;
    unsigned short* w_op2 = Wb + 262144;
    unsigned short* w_om1 = Wb + 327680;
    unsigned short* w_om2 = Wb + 344064;
    unsigned short* w_fc1 = Wb + 360448;
    unsigned short* w_fc2 = Wb + 557056;

    // 0. weights -> bf16
    wconv_kernel<<<736, 256, 0, stream>>>(q_w, kv_w, op1_w, op2_w, om1_w, om2_w, fc1_w, fc2_w, Wb);
    // 1. xn = std_ln(x, norm1)
    stdln_kernel<false><<<2048, 256, 0, stream>>>(x, n1_w, n1_b, XN);
    // 2. kv = xr @ kv_w.T (swapped rows), split K,V — WN=8 full width
    mgemm<M_KV, true, 256, 512, 8><<<dim3(512, 1), 1024, 0, stream>>>(XN, w_kv, nullptr, nullptr, nullptr, nullptr, Kb, Vb);
    // 3. ce_flat
    ce_kernel<<<2048, 256, 0, stream>>>(cor, cor_w, CEF);
    // 4. zero accumulators
    hipMemsetAsync(KTV, 0, (32768 + 16384) * sizeof(float), stream);
    // 5. fused LN + ktv + ktc (register-tiled)
    ktvc_kernel<<<dim3(32, 32), 256, 0, stream>>>(Kb, Vb, CEF, kln_w, kln_b, vln_w, vln_b,
                                                  corln_w, corln_b, KTV, KTC);
    // 6. combined attention weights WTC[b] = q_w^T · blockdiag(ktv|ktc)
    wcomb_kernel<<<dim3(384, 4), 256, 0, stream>>>(q_w, KTV, KTC, WTC);
    // 7. [t | dm] = xn @ WTC[b] (+xn | -ce_flat) — WN=6 full width
    mgemm<M_ATTN, false, 256, 384, 6><<<dim3(512, 1), 768, 0, stream>>>(XN, WTC, (const float*)CEF, XN, nullptr, nullptr, T1, TM);
    // 8. hidden = gelu(t @ op1.T + b) — WN=4
    mgemm<M_BIAS_GELU, false, 256, 256, 4><<<dim3(512, 1), 512, 0, stream>>>(T1, w_op1, op1_b, nullptr, nullptr, nullptr, T2, nullptr);
    // 9. Y = LN2((hidden @ op2.T + b) + 2*xn) — fused op2+LN, WN=4 full width; Y=Vb
    mgemm<M_ADD2LN, false, 256, 256, 4><<<dim3(512, 1), 512, 0, stream>>>(T2, w_op2, op2_b, XN, n2_w, n2_b, Y, nullptr);
    // 10. motion = gelu(dm @ om1.T + b1) @ om2.T + b2 -> output 1 (fused, LDS-resident mh)
    motion_kernel<<<512, 256, 0, stream>>>(TM, w_om1, om1_b, w_om2, om2_b, mout);
    // 11. h1 = y @ fc1.T + b (bf16) — WN=6, y=2; H1 = XN-span overlay (L3-warm)
    mgemm<M_BIAS_BF16, false, 256, 768, 6><<<dim3(512, 2), 768, 0, stream>>>(Y, w_fc1, fc1_b, nullptr, nullptr, nullptr, H1, nullptr);
    // 12. depthwise conv + bias + gelu (y-banded, 16-col chunks, 1024 blocks)
    dwconv_kernel<<<1024, 192, 0, stream>>>(H1, dw_w, dw_b, H2);
    // 13. x_out = h2 @ fc2.T + b + x -> output 0 (fp32) — WN=4 (r16 best config)
    mgemm<M_BIAS_ADDX, false, 768, 256, 4><<<dim3(512, 1), 512, 0, stream>>>(H2, w_fc2, fc2_b, x, nullptr, nullptr, xout, nullptr);
}